// Round 14
// baseline (26.694 us; speedup 1.0000x reference)
//
#include <hip/hip_runtime.h>
#include <float.h>

static constexpr int H    = 2048;
static constexpr int Wd   = 2048;
static constexpr int NPIX = H * Wd;
static constexpr int BT   = 256;                 // threads per block
static constexpr int N4   = NPIX / 4;

static constexpr int NB1   = 2048;               // stage-1 blocks: 8/CU, 32 waves/CU
static constexpr int ITER1 = N4 / (NB1 * BT);    // == 2, exact
static constexpr int NB2   = 2048;               // stage-3 blocks
static constexpr int ITER2 = N4 / (NB2 * BT);    // == 2, exact

typedef float f32x4 __attribute__((ext_vector_type(4)));  // native vecs for nt builtins
typedef int   i32x4 __attribute__((ext_vector_type(4)));

// ws layout (floats, SoA, NO atomics/counters anywhere):
//   partials p[s*NB1 + b], s in [0,12)  -- all rewritten every call
//   ratio at p + 12*NB1                 -- rewritten every call by finalize
// slots: [0..2] sparse min {x*z, y*z, z} (unscaled by 1/fx,1/fy),
//        [3..5] sparse max, [6..8] dense min, [9..11] dense max.
// Cross-kernel visibility: plain/nt stores + kernel-boundary ordering
// (proven R2/R3/R6/R10/R12/R13; in-kernel cross-XCD sync costs 40-80us:
//  R1 atomic burst, R4 cg::sync, R5 acquire-spin, R7 relaxed-spin, R9 acq_rel.
//  Broadcast-fin at NB1=2048 costs +1.8us vs dedicated fin: R11.)
// R13 delta (+1.0us): nt-loads for read-once sparse/mask streams.
// R14 delta: nt-load for k3's dense (last read) + nt-store for k1 partials.

__global__ __launch_bounds__(BT) void reduce_bbox_kernel(
    const float* __restrict__ dense,
    const float* __restrict__ sparse,
    const int*   __restrict__ mask,
    const float* __restrict__ intr,
    float* __restrict__ ws)
{
    const float cx = intr[2], cy = intr[3];
    const float qnan = __uint_as_float(0x7FC00000u);

    const f32x4* d4 = (const f32x4*)dense;
    const f32x4* s4 = (const f32x4*)sparse;
    const i32x4* m4 = (const i32x4*)mask;

    const int tid = blockIdx.x * BT + threadIdx.x;

    float loc[12];
#pragma unroll
    for (int s = 0; s < 12; ++s) loc[s] = ((s % 6) < 3) ? FLT_MAX : -FLT_MAX;

    // batched loads: all 6 vector loads in flight, then consume.
    // sparse/mask are read-once -> nontemporal (no L2 allocation);
    // dense is re-read by k3 -> normal cached load (stays LLC-resident).
    i32x4 mv[ITER1];
    f32x4 sv[ITER1];
    f32x4 dv[ITER1];
#pragma unroll
    for (int k = 0; k < ITER1; ++k) {
        const int i = tid + k * (NB1 * BT);
        mv[k] = __builtin_nontemporal_load(&m4[i]);
        sv[k] = __builtin_nontemporal_load(&s4[i]);
        dv[k] = d4[i];
    }

#pragma unroll
    for (int k = 0; k < ITER1; ++k) {
        const int i = tid + k * (NB1 * BT);
        const int base = i << 2;                 // 2048 % 4 == 0: row never split
        const float yc = (float)(base >> 11) - cy;
        const float xf = (float)(base & 2047);
#pragma unroll
        for (int j = 0; j < 4; ++j) {
            // NaN sentinel: v_min/v_max (IEEE) return the non-NaN operand,
            // so masked-out pixels are no-ops -> branchless.
            float sd = (mv[k][j] != 0) ? sv[k][j] : qnan;
            float de = (mv[k][j] != 0) ? dv[k][j] : qnan;
            float xc = xf + (float)j - cx;
            float spx = xc * sd;
            float spy = yc * sd;
            float dpx = xc * de;
            float dpy = yc * de;
            loc[0] = fminf(loc[0], spx); loc[3]  = fmaxf(loc[3],  spx);
            loc[1] = fminf(loc[1], spy); loc[4]  = fmaxf(loc[4],  spy);
            loc[2] = fminf(loc[2], sd ); loc[5]  = fmaxf(loc[5],  sd );
            loc[6] = fminf(loc[6], dpx); loc[9]  = fmaxf(loc[9],  dpx);
            loc[7] = fminf(loc[7], dpy); loc[10] = fmaxf(loc[10], dpy);
            loc[8] = fminf(loc[8], de ); loc[11] = fmaxf(loc[11], de );
        }
    }

    // wave-64 butterfly
#pragma unroll
    for (int off = 32; off > 0; off >>= 1) {
#pragma unroll
        for (int s = 0; s < 12; ++s) {
            float o = __shfl_xor(loc[s], off, 64);
            loc[s] = ((s % 6) < 3) ? fminf(loc[s], o) : fmaxf(loc[s], o);
        }
    }

    __shared__ float red[4][12];
    const int lane = threadIdx.x & 63;
    const int wid  = threadIdx.x >> 6;
    if (lane == 0) {
#pragma unroll
        for (int s = 0; s < 12; ++s) red[wid][s] = loc[s];
    }
    __syncthreads();

    if (threadIdx.x < 12) {
        const int s = threadIdx.x;
        const bool is_min = (s % 6) < 3;
        float v = red[0][s];
#pragma unroll
        for (int w = 1; w < 4; ++w)
            v = is_min ? fminf(v, red[w][s]) : fmaxf(v, red[w][s]);
        // nt-store: consumed once by fin through LLC; visibility via
        // kernel-boundary release (same guarantee as the out nt-stores).
        __builtin_nontemporal_store(v, &ws[s * NB1 + blockIdx.x]);
    }
}

// Stage 2 (1 block): reduce 12 x NB1 partials, publish ratio + std.
__global__ __launch_bounds__(BT) void finalize_kernel(
    const float* __restrict__ ws,
    const float* __restrict__ intr,
    float* __restrict__ ratio_p,
    float* __restrict__ out)
{
    static_assert(NB1 / 4 == 2 * BT, "two float4 per thread per slot");
    const float4* p4 = (const float4*)ws;
    float loc[12];
#pragma unroll
    for (int s = 0; s < 12; ++s) {
        float4 a = p4[s * (NB1 / 4) + threadIdx.x];
        float4 b = p4[s * (NB1 / 4) + BT + threadIdx.x];
        if ((s % 6) < 3)
            loc[s] = fminf(fminf(fminf(a.x, a.y), fminf(a.z, a.w)),
                           fminf(fminf(b.x, b.y), fminf(b.z, b.w)));
        else
            loc[s] = fmaxf(fmaxf(fmaxf(a.x, a.y), fmaxf(a.z, a.w)),
                           fmaxf(fmaxf(b.x, b.y), fmaxf(b.z, b.w)));
    }

#pragma unroll
    for (int off = 32; off > 0; off >>= 1) {
#pragma unroll
        for (int s = 0; s < 12; ++s) {
            float o = __shfl_xor(loc[s], off, 64);
            loc[s] = ((s % 6) < 3) ? fminf(loc[s], o) : fmaxf(loc[s], o);
        }
    }

    __shared__ float red[4][12];
    const int lane = threadIdx.x & 63;
    const int wid  = threadIdx.x >> 6;
    if (lane == 0) {
#pragma unroll
        for (int s = 0; s < 12; ++s) red[wid][s] = loc[s];
    }
    __syncthreads();

    if (threadIdx.x == 0) {
        float fin[12];
#pragma unroll
        for (int s = 0; s < 12; ++s) {
            const bool is_min = (s % 6) < 3;
            float v = red[0][s];
#pragma unroll
            for (int w = 1; w < 4; ++w)
                v = is_min ? fminf(v, red[w][s]) : fmaxf(v, red[w][s]);
            fin[s] = v;
        }
        const float inv_fx = 1.0f / intr[0], inv_fy = 1.0f / intr[1];
        float sx = (fin[3]  - fin[0]) * inv_fx;
        float sy = (fin[4]  - fin[1]) * inv_fy;
        float sz =  fin[5]  - fin[2];
        float dx = (fin[9]  - fin[6]) * inv_fx;
        float dy = (fin[10] - fin[7]) * inv_fy;
        float dz =  fin[11] - fin[8];
        ratio_p[0] = sqrtf(sx*sx + sy*sy + sz*sz) /
                     sqrtf(dx*dx + dy*dy + dz*dz);   // plain store
        out[NPIX] = 1.0f;  // std
    }
}

// Stage 3: pure streaming scale. dense is LLC-warm from k1 and this is its
// LAST read -> nt-load (no L2 allocation); nt-stores for the write stream.
__global__ __launch_bounds__(BT) void scale_kernel(
    const float* __restrict__ dense,
    const float* __restrict__ ratio_p,
    float* __restrict__ out)
{
    const int tid = blockIdx.x * BT + threadIdx.x;
    const f32x4* d4 = (const f32x4*)dense;

    // dense loads in flight before the ratio pickup
    f32x4 v0 = __builtin_nontemporal_load(&d4[tid]);
    f32x4 v1 = __builtin_nontemporal_load(&d4[tid + NB2 * BT]);

    __shared__ float rs;
    if (threadIdx.x == 0) rs = ratio_p[0];   // plain load; kernel boundary ordered
    __syncthreads();
    const float r = rs;

    f32x4* o4 = (f32x4*)out;
    f32x4 r0 = v0 * r;
    f32x4 r1 = v1 * r;
    __builtin_nontemporal_store(r0, &o4[tid]);
    __builtin_nontemporal_store(r1, &o4[tid + NB2 * BT]);
}

extern "C" void kernel_launch(void* const* d_in, const int* in_sizes, int n_in,
                              void* d_out, int out_size, void* d_ws, size_t ws_size,
                              hipStream_t stream) {
    const float* dense  = (const float*)d_in[0];  // depth_estimations
    const float* sparse = (const float*)d_in[1];  // sparse_depths
    const int*   mask   = (const int*)d_in[2];    // sparse_depth_masks
    const float* intr   = (const float*)d_in[3];  // intrinsics

    float* out   = (float*)d_out;
    float* ws_f  = (float*)d_ws;
    float* ratio = ws_f + 12 * NB1;

    reduce_bbox_kernel<<<NB1, BT, 0, stream>>>(dense, sparse, mask, intr, ws_f);
    finalize_kernel<<<1, BT, 0, stream>>>(ws_f, intr, ratio, out);
    scale_kernel<<<NB2, BT, 0, stream>>>(dense, ratio, out);
}

// Round 15
// 22.807 us; speedup vs baseline: 1.1704x; 1.1704x over previous
//
#include <hip/hip_runtime.h>
#include <float.h>

static constexpr int H    = 2048;
static constexpr int Wd   = 2048;
static constexpr int NPIX = H * Wd;
static constexpr int BT   = 256;                 // threads per block
static constexpr int N4   = NPIX / 4;

static constexpr int NB1   = 2048;               // stage-1 blocks: 8/CU, 32 waves/CU
static constexpr int ITER1 = N4 / (NB1 * BT);    // == 2, exact
static constexpr int NB2   = 2048;               // stage-3 blocks
static constexpr int ITER2 = N4 / (NB2 * BT);    // == 2, exact

typedef float f32x4 __attribute__((ext_vector_type(4)));  // native vecs for nt builtins
typedef int   i32x4 __attribute__((ext_vector_type(4)));

// ws layout (floats, SoA, NO atomics/counters anywhere):
//   partials p[s*NB1 + b], s in [0,12)  -- all rewritten every call
//   ratio at p + 12*NB1                 -- rewritten every call by finalize
// slots: [0..2] sparse min {x*z, y*z, z} (unscaled by 1/fx,1/fy),
//        [3..5] sparse max, [6..8] dense min, [9..11] dense max.
// Cross-kernel visibility: plain stores + kernel-boundary ordering
// (proven R2/R3/R6/R10/R12/R13; in-kernel cross-XCD sync costs 40-80us:
//  R1 atomic burst, R4 cg::sync, R5 acquire-spin, R7 relaxed-spin, R9 acq_rel.
//  Broadcast-fin at NB1=2048 costs +1.8us vs dedicated fin: R11.)
// nt-hint boundary (R13 win −1.0us, R14 regression +3.8us): nt-load ONLY for
// first-and-only reads (sparse/mask); nt-store ONLY for data no kernel reads
// this call (out). Dense and partials have downstream reuse -> stay cached.

__global__ __launch_bounds__(BT) void reduce_bbox_kernel(
    const float* __restrict__ dense,
    const float* __restrict__ sparse,
    const int*   __restrict__ mask,
    const float* __restrict__ intr,
    float* __restrict__ ws)
{
    const float cx = intr[2], cy = intr[3];
    const float qnan = __uint_as_float(0x7FC00000u);

    const f32x4* d4 = (const f32x4*)dense;
    const f32x4* s4 = (const f32x4*)sparse;
    const i32x4* m4 = (const i32x4*)mask;

    const int tid = blockIdx.x * BT + threadIdx.x;

    float loc[12];
#pragma unroll
    for (int s = 0; s < 12; ++s) loc[s] = ((s % 6) < 3) ? FLT_MAX : -FLT_MAX;

    // batched loads: all 6 vector loads in flight, then consume.
    // sparse/mask are read-once -> nontemporal (no L2 allocation);
    // dense is re-read by k3 -> normal cached load (stays LLC-resident).
    i32x4 mv[ITER1];
    f32x4 sv[ITER1];
    f32x4 dv[ITER1];
#pragma unroll
    for (int k = 0; k < ITER1; ++k) {
        const int i = tid + k * (NB1 * BT);
        mv[k] = __builtin_nontemporal_load(&m4[i]);
        sv[k] = __builtin_nontemporal_load(&s4[i]);
        dv[k] = d4[i];
    }

#pragma unroll
    for (int k = 0; k < ITER1; ++k) {
        const int i = tid + k * (NB1 * BT);
        const int base = i << 2;                 // 2048 % 4 == 0: row never split
        const float yc = (float)(base >> 11) - cy;
        const float xf = (float)(base & 2047);
#pragma unroll
        for (int j = 0; j < 4; ++j) {
            // NaN sentinel: v_min/v_max (IEEE) return the non-NaN operand,
            // so masked-out pixels are no-ops -> branchless.
            float sd = (mv[k][j] != 0) ? sv[k][j] : qnan;
            float de = (mv[k][j] != 0) ? dv[k][j] : qnan;
            float xc = xf + (float)j - cx;
            float spx = xc * sd;
            float spy = yc * sd;
            float dpx = xc * de;
            float dpy = yc * de;
            loc[0] = fminf(loc[0], spx); loc[3]  = fmaxf(loc[3],  spx);
            loc[1] = fminf(loc[1], spy); loc[4]  = fmaxf(loc[4],  spy);
            loc[2] = fminf(loc[2], sd ); loc[5]  = fmaxf(loc[5],  sd );
            loc[6] = fminf(loc[6], dpx); loc[9]  = fmaxf(loc[9],  dpx);
            loc[7] = fminf(loc[7], dpy); loc[10] = fmaxf(loc[10], dpy);
            loc[8] = fminf(loc[8], de ); loc[11] = fmaxf(loc[11], de );
        }
    }

    // wave-64 butterfly
#pragma unroll
    for (int off = 32; off > 0; off >>= 1) {
#pragma unroll
        for (int s = 0; s < 12; ++s) {
            float o = __shfl_xor(loc[s], off, 64);
            loc[s] = ((s % 6) < 3) ? fminf(loc[s], o) : fmaxf(loc[s], o);
        }
    }

    __shared__ float red[4][12];
    const int lane = threadIdx.x & 63;
    const int wid  = threadIdx.x >> 6;
    if (lane == 0) {
#pragma unroll
        for (int s = 0; s < 12; ++s) red[wid][s] = loc[s];
    }
    __syncthreads();

    if (threadIdx.x < 12) {
        const int s = threadIdx.x;
        const bool is_min = (s % 6) < 3;
        float v = red[0][s];
#pragma unroll
        for (int w = 1; w < 4; ++w)
            v = is_min ? fminf(v, red[w][s]) : fmaxf(v, red[w][s]);
        ws[s * NB1 + blockIdx.x] = v;   // plain store, no atomics
    }
}

// Stage 2 (1 block): reduce 12 x NB1 partials, publish ratio + std.
__global__ __launch_bounds__(BT) void finalize_kernel(
    const float* __restrict__ ws,
    const float* __restrict__ intr,
    float* __restrict__ ratio_p,
    float* __restrict__ out)
{
    static_assert(NB1 / 4 == 2 * BT, "two float4 per thread per slot");
    const float4* p4 = (const float4*)ws;
    float loc[12];
#pragma unroll
    for (int s = 0; s < 12; ++s) {
        float4 a = p4[s * (NB1 / 4) + threadIdx.x];
        float4 b = p4[s * (NB1 / 4) + BT + threadIdx.x];
        if ((s % 6) < 3)
            loc[s] = fminf(fminf(fminf(a.x, a.y), fminf(a.z, a.w)),
                           fminf(fminf(b.x, b.y), fminf(b.z, b.w)));
        else
            loc[s] = fmaxf(fmaxf(fmaxf(a.x, a.y), fmaxf(a.z, a.w)),
                           fmaxf(fmaxf(b.x, b.y), fmaxf(b.z, b.w)));
    }

#pragma unroll
    for (int off = 32; off > 0; off >>= 1) {
#pragma unroll
        for (int s = 0; s < 12; ++s) {
            float o = __shfl_xor(loc[s], off, 64);
            loc[s] = ((s % 6) < 3) ? fminf(loc[s], o) : fmaxf(loc[s], o);
        }
    }

    __shared__ float red[4][12];
    const int lane = threadIdx.x & 63;
    const int wid  = threadIdx.x >> 6;
    if (lane == 0) {
#pragma unroll
        for (int s = 0; s < 12; ++s) red[wid][s] = loc[s];
    }
    __syncthreads();

    if (threadIdx.x == 0) {
        float fin[12];
#pragma unroll
        for (int s = 0; s < 12; ++s) {
            const bool is_min = (s % 6) < 3;
            float v = red[0][s];
#pragma unroll
            for (int w = 1; w < 4; ++w)
                v = is_min ? fminf(v, red[w][s]) : fmaxf(v, red[w][s]);
            fin[s] = v;
        }
        const float inv_fx = 1.0f / intr[0], inv_fy = 1.0f / intr[1];
        float sx = (fin[3]  - fin[0]) * inv_fx;
        float sy = (fin[4]  - fin[1]) * inv_fy;
        float sz =  fin[5]  - fin[2];
        float dx = (fin[9]  - fin[6]) * inv_fx;
        float dy = (fin[10] - fin[7]) * inv_fy;
        float dz =  fin[11] - fin[8];
        ratio_p[0] = sqrtf(sx*sx + sy*sy + sz*sz) /
                     sqrtf(dx*dx + dy*dy + dz*dz);   // plain store
        out[NPIX] = 1.0f;  // std
    }
}

// Stage 3: pure streaming scale. dense is L3-warm from k1 (cached load);
// nontemporal stores keep the output from evicting LLC-resident inputs.
__global__ __launch_bounds__(BT) void scale_kernel(
    const float* __restrict__ dense,
    const float* __restrict__ ratio_p,
    float* __restrict__ out)
{
    const int tid = blockIdx.x * BT + threadIdx.x;
    const f32x4* d4 = (const f32x4*)dense;

    // dense loads in flight before the ratio pickup
    f32x4 v0 = d4[tid];
    f32x4 v1 = d4[tid + NB2 * BT];

    __shared__ float rs;
    if (threadIdx.x == 0) rs = ratio_p[0];   // plain load; kernel boundary ordered
    __syncthreads();
    const float r = rs;

    f32x4* o4 = (f32x4*)out;
    f32x4 r0 = v0 * r;
    f32x4 r1 = v1 * r;
    __builtin_nontemporal_store(r0, &o4[tid]);
    __builtin_nontemporal_store(r1, &o4[tid + NB2 * BT]);
}

extern "C" void kernel_launch(void* const* d_in, const int* in_sizes, int n_in,
                              void* d_out, int out_size, void* d_ws, size_t ws_size,
                              hipStream_t stream) {
    const float* dense  = (const float*)d_in[0];  // depth_estimations
    const float* sparse = (const float*)d_in[1];  // sparse_depths
    const int*   mask   = (const int*)d_in[2];    // sparse_depth_masks
    const float* intr   = (const float*)d_in[3];  // intrinsics

    float* out   = (float*)d_out;
    float* ws_f  = (float*)d_ws;
    float* ratio = ws_f + 12 * NB1;

    reduce_bbox_kernel<<<NB1, BT, 0, stream>>>(dense, sparse, mask, intr, ws_f);
    finalize_kernel<<<1, BT, 0, stream>>>(ws_f, intr, ratio, out);
    scale_kernel<<<NB2, BT, 0, stream>>>(dense, ratio, out);
}